// Round 5
// baseline (354.350 us; speedup 1.0000x reference)
//
#include <hip/hip_runtime.h>
#include <hip/hip_cooperative_groups.h>

// LightCoordAtt: x (N,C,H,W) f32 in, f32 out. N=16, C=256, H=W=80, mip=8, L=160.
//
// R5: single cooperative kernel. Rationale: aggregate VGPR (134 MB) > x
// (105 MB), so x can live in registers across the grid-wide dependency.
//   phase1: block owns 8 planes of one n; 50 coalesced float4 loads/thread
//           into qx[50] (200 VGPR); per-plane LDS stage + row/col mean ->
//           pooled_t[n][l][c] (transposed: c fastest, for coalesced phase2a)
//   sync1
//   phase2a: mid GEMM distributed: 2560 (n,l) pairs, 5 per block, mid-style
//            shuffle reduce (NO cross-XCD atomics - R1 lesson) -> y[n][l][m]
//   sync2
//   phase2b: 8x160 gates per block from y (L2-hot) -> LDS
//   phase3 : out = qx * lah[plane][row] * law4 (one aligned b128 LDS read,
//            ~3-way, vs 4x b32) ; NT stores (write-once).
// Geometry: 512 blocks x 256 thr = 2048 waves = 2/SIMD exactly co-resident
// at __launch_bounds__(256,2); LDS 25.9 KB (not binding).
// Fallback: if hipLaunchCooperativeKernel is rejected (capture/occupancy),
// run the proven R4 3-kernel path (220.9 us).
#define N_   16
#define C_   256
#define H_   80
#define W_   80
#define MIP_ 8
#define L_   160

typedef float f32x4 __attribute__((ext_vector_type(4)));

namespace cg = cooperative_groups;

// ---------------------------------------------------------------------------
// Fused cooperative kernel.
// ---------------------------------------------------------------------------
__global__ __launch_bounds__(256, 2) void fused_kernel(
    const float* __restrict__ x,
    const float* __restrict__ w_fc,
    const float* __restrict__ g,
    const float* __restrict__ be,
    const float* __restrict__ mu,
    const float* __restrict__ va,
    const float* __restrict__ w_h,
    const float* __restrict__ w_w,
    float* __restrict__ pooled_t,     // [N][L][C] f32 (2.62 MB ws)
    float* __restrict__ y_glob,       // [N][L][MIP] f32 (80 KB ws)
    float* __restrict__ out)
{
    __shared__ float smem[H_ * 81];   // 25920 B; phase1: [80][81] staging
    // phase2b/3 aliases (staging dead by then):
    float* lah = smem;                        // [8][80]
    float* law = smem + 8 * H_;               // [8][80]  (offset 2560 B, 16B-aligned)
    float* red = smem + 16 * H_;              // [4][8] cross-wave partials

    const int b    = blockIdx.x;              // 0..511
    const int n    = b >> 5;                  // 16 n
    const int c0   = (b & 31) << 3;           // 8 channels per block
    const int t    = threadIdx.x;
    const int wv   = t >> 6;                  // wave 0..3 owns planes 2wv,2wv+1
    const int lane = t & 63;

    // ---- phase 1: load 8 planes (51200 floats) into registers, coalesced ----
    const f32x4* xv = reinterpret_cast<const f32x4*>(x + ((size_t)n * C_ + c0) * (H_ * W_));
    f32x4 qx[50];
    #pragma unroll
    for (int j = 0; j < 50; ++j)
        qx[j] = xv[wv * 3200 + 64 * j + lane];   // wave-contiguous 1KB per instr

    // per plane: owning wave stages regs->LDS, all waves reduce
    #pragma unroll
    for (int p = 0; p < 8; ++p) {
        if (wv == (p >> 1)) {                    // wave-uniform branch
            const int jb = (p & 1) * 25;
            #pragma unroll
            for (int k = 0; k < 25; ++k) {
                int o    = lane + 64 * k;        // float4 offset within plane
                int row  = o / 20;
                int col0 = (o - row * 20) * 4;
                float* dst = &smem[row * 81 + col0];
                f32x4 q = qx[jb + k];
                dst[0] = q.x; dst[1] = q.y; dst[2] = q.z; dst[3] = q.w;
            }
        }
        __syncthreads();
        const int c = c0 + p;
        if (t < H_) {                            // row means -> x_h
            float s0 = 0.f, s1 = 0.f, s2 = 0.f, s3 = 0.f;
            const float* r = &smem[t * 81];
            #pragma unroll
            for (int c4 = 0; c4 < W_; c4 += 4) {
                s0 += r[c4]; s1 += r[c4 + 1]; s2 += r[c4 + 2]; s3 += r[c4 + 3];
            }
            pooled_t[((size_t)n * L_ + t) * C_ + c] = (s0 + s1 + s2 + s3) * (1.0f / (float)W_);
        } else if (t >= 128 && t < 128 + W_) {   // col means -> x_w
            const int j2 = t - 128;
            float s0 = 0.f, s1 = 0.f, s2 = 0.f, s3 = 0.f;
            #pragma unroll
            for (int r4 = 0; r4 < H_; r4 += 4) {
                s0 += smem[(r4    ) * 81 + j2];
                s1 += smem[(r4 + 1) * 81 + j2];
                s2 += smem[(r4 + 2) * 81 + j2];
                s3 += smem[(r4 + 3) * 81 + j2];
            }
            pooled_t[((size_t)n * L_ + H_ + j2) * C_ + c] = (s0 + s1 + s2 + s3) * (1.0f / (float)H_);
        }
        __syncthreads();
    }

    cg::this_grid().sync();   // pooled_t complete & visible device-wide

    // ---- phase 2a: mid GEMM, 5 (n,l) pairs per block, shuffle reduce ----
    {
        float wfr[MIP_];
        #pragma unroll
        for (int m = 0; m < MIP_; ++m) wfr[m] = w_fc[m * C_ + t];   // c = t
        #pragma unroll
        for (int i = 0; i < 5; ++i) {
            const int pair = b * 5 + i;          // 0..2559
            const int np   = pair / L_;
            const int lp   = pair - np * L_;
            const float pch = pooled_t[((size_t)np * L_ + lp) * C_ + t];  // coalesced
            #pragma unroll
            for (int m = 0; m < MIP_; ++m) {
                float v = wfr[m] * pch;
                #pragma unroll
                for (int off = 32; off > 0; off >>= 1) v += __shfl_down(v, off, 64);
                if (lane == 0) red[wv * MIP_ + m] = v;
            }
            __syncthreads();
            if (t < MIP_) {
                float s   = red[t] + red[MIP_ + t] + red[2 * MIP_ + t] + red[3 * MIP_ + t];
                float inv = g[t] * rsqrtf(va[t] + 1e-5f);
                s = s * inv + (be[t] - mu[t] * inv);
                y_glob[(size_t)pair * MIP_ + t] = s / (1.0f + expf(-s));   // swish
            }
            __syncthreads();                     // red reused next i
        }
    }

    cg::this_grid().sync();   // y complete & visible device-wide

    // ---- phase 2b: gates for this block's 8 channels ----
    if (t < L_) {
        const f32x4* yp = reinterpret_cast<const f32x4*>(y_glob + ((size_t)n * L_ + t) * MIP_);
        f32x4 ya = yp[0], yb = yp[1];            // L2-hot, coalesced 32B/thread
        const float* wbase = (t < H_) ? w_h : w_w;
        #pragma unroll
        for (int ch = 0; ch < 8; ++ch) {
            const f32x4* wp = reinterpret_cast<const f32x4*>(wbase + (size_t)(c0 + ch) * MIP_);
            f32x4 w0 = wp[0], w1 = wp[1];
            float s = ya.x * w0.x + ya.y * w0.y + ya.z * w0.z + ya.w * w0.w
                    + yb.x * w1.x + yb.y * w1.y + yb.z * w1.z + yb.w * w1.w;
            float gate = 1.0f / (1.0f + expf(-s));
            if (t < H_) lah[ch * H_ + t]        = gate;
            else        law[ch * W_ + (t - H_)] = gate;
        }
    }
    __syncthreads();

    // ---- phase 3: out = qx * ah * aw, NT float4 stores ----
    f32x4* ovb = reinterpret_cast<f32x4*>(out + ((size_t)n * C_ + c0) * (H_ * W_));
    #pragma unroll
    for (int j = 0; j < 50; ++j) {
        const int q25   = (j >= 25) ? 1 : 0;
        const int o     = lane + 64 * (j - 25 * q25);     // float4 offset in plane
        const int plane = 2 * wv + q25;
        const int row   = o / 20;
        const int col4  = o - row * 20;
        const float gr  = lah[plane * H_ + row];          // ~broadcast b32
        const f32x4 gc  = *reinterpret_cast<const f32x4*>(&law[plane * W_ + col4 * 4]); // 1 b128
        f32x4 q = qx[j], r;
        r.x = q.x * gr * gc.x; r.y = q.y * gr * gc.y;
        r.z = q.z * gr * gc.z; r.w = q.w * gr * gc.w;
        __builtin_nontemporal_store(r, &ovb[wv * 3200 + 64 * j + lane]);
    }
}

// ---------------------------------------------------------------------------
// Fallback path = R4 (220.9 us), used only if cooperative launch is rejected.
// ---------------------------------------------------------------------------
__global__ __launch_bounds__(256) void pool_kernel(const float* __restrict__ x,
                                                   float* __restrict__ pooled) {
    __shared__ float lds[H_ * 81];
    const int b = blockIdx.x;
    const int t = threadIdx.x;
    const float4* pv = reinterpret_cast<const float4*>(x + (size_t)b * (H_ * W_));
    #pragma unroll
    for (int it = 0; it < 7; ++it) {
        int v = t + it * 256;
        if (v < 1600) {
            float4 q = pv[v];
            int row  = v / 20;
            int col0 = (v - row * 20) * 4;
            float* dst = &lds[row * 81 + col0];
            dst[0] = q.x; dst[1] = q.y; dst[2] = q.z; dst[3] = q.w;
        }
    }
    __syncthreads();
    float* outp = pooled + (size_t)b * L_;
    if (t < H_) {
        float s0 = 0.f, s1 = 0.f, s2 = 0.f, s3 = 0.f;
        const float* r = &lds[t * 81];
        #pragma unroll
        for (int c4 = 0; c4 < W_; c4 += 4) {
            s0 += r[c4]; s1 += r[c4 + 1]; s2 += r[c4 + 2]; s3 += r[c4 + 3];
        }
        outp[t] = (s0 + s1 + s2 + s3) * (1.0f / (float)W_);
    } else if (t >= 128 && t < 128 + W_) {
        const int j = t - 128;
        float s0 = 0.f, s1 = 0.f, s2 = 0.f, s3 = 0.f;
        #pragma unroll
        for (int r4 = 0; r4 < H_; r4 += 4) {
            s0 += lds[(r4    ) * 81 + j];
            s1 += lds[(r4 + 1) * 81 + j];
            s2 += lds[(r4 + 2) * 81 + j];
            s3 += lds[(r4 + 3) * 81 + j];
        }
        outp[H_ + j] = (s0 + s1 + s2 + s3) * (1.0f / (float)H_);
    }
}

__global__ __launch_bounds__(256) void mid_kernel(const float* __restrict__ pooled,
                                                  const float* __restrict__ w_fc,
                                                  const float* __restrict__ g,
                                                  const float* __restrict__ be,
                                                  const float* __restrict__ mu,
                                                  const float* __restrict__ va,
                                                  float* __restrict__ y_out) {
    __shared__ float red[4 * MIP_];
    const int b    = blockIdx.x;
    const int n    = b / L_;
    const int l    = b - n * L_;
    const int c    = threadIdx.x;
    const int lane = c & 63;
    const int wid  = c >> 6;
    const float p = pooled[((size_t)n * C_ + c) * L_ + l];
    #pragma unroll
    for (int m = 0; m < MIP_; ++m) {
        float v = w_fc[m * C_ + c] * p;
        #pragma unroll
        for (int off = 32; off > 0; off >>= 1) v += __shfl_down(v, off, 64);
        if (lane == 0) red[wid * MIP_ + m] = v;
    }
    __syncthreads();
    if (c < MIP_) {
        float y   = red[c] + red[MIP_ + c] + red[2 * MIP_ + c] + red[3 * MIP_ + c];
        float inv = g[c] * rsqrtf(va[c] + 1e-5f);
        y = y * inv + (be[c] - mu[c] * inv);
        y_out[(size_t)b * MIP_ + c] = y / (1.0f + expf(-y));
    }
}

__global__ __launch_bounds__(256) void apply_kernel(const float* __restrict__ x,
                                                    const float* __restrict__ y,
                                                    const float* __restrict__ w_h,
                                                    const float* __restrict__ w_w,
                                                    float* __restrict__ out) {
    __shared__ float lah[4][H_];
    __shared__ float law[4][W_];
    const int b  = blockIdx.x;
    const int n  = b >> 6;
    const int c0 = (b & 63) << 2;
    const int t  = threadIdx.x;
    #pragma unroll
    for (int pass = 0; pass < 3; ++pass) {
        int idx = t + pass * 256;
        if (idx < 4 * L_) {
            int ch = idx / L_;
            int l  = idx - ch * L_;
            int c  = c0 + ch;
            const float4* yp = reinterpret_cast<const float4*>(y + ((size_t)n * L_ + l) * MIP_);
            const float4* wp = reinterpret_cast<const float4*>(((l < H_) ? w_h : w_w) + c * MIP_);
            float4 y0 = yp[0], y1 = yp[1];
            float4 w0 = wp[0], w1 = wp[1];
            float s = y0.x * w0.x + y0.y * w0.y + y0.z * w0.z + y0.w * w0.w
                    + y1.x * w1.x + y1.y * w1.y + y1.z * w1.z + y1.w * w1.w;
            float gate = 1.0f / (1.0f + expf(-s));
            if (l < H_) lah[ch][l] = gate; else law[ch][l - H_] = gate;
        }
    }
    __syncthreads();
    const float4* xv = reinterpret_cast<const float4*>(x + ((size_t)n * C_ + c0) * (H_ * W_));
    f32x4*        ov = reinterpret_cast<f32x4*>(out + ((size_t)n * C_ + c0) * (H_ * W_));
    #pragma unroll
    for (int it = 0; it < 25; ++it) {
        int v     = t + it * 256;
        int plane = v / 1600;
        int vv    = v - plane * 1600;
        int row   = vv / 20;
        int col0  = (vv - row * 20) * 4;
        float4 q  = xv[v];
        const float ah = lah[plane][row];
        const float* lw = &law[plane][col0];
        f32x4 o;
        o.x = q.x * ah * lw[0];
        o.y = q.y * ah * lw[1];
        o.z = q.z * ah * lw[2];
        o.w = q.w * ah * lw[3];
        __builtin_nontemporal_store(o, &ov[v]);
    }
}

extern "C" void kernel_launch(void* const* d_in, const int* in_sizes, int n_in,
                              void* d_out, int out_size, void* d_ws, size_t ws_size,
                              hipStream_t stream) {
    const float* x    = (const float*)d_in[0];
    const float* w_fc = (const float*)d_in[1];
    const float* g    = (const float*)d_in[2];
    const float* be   = (const float*)d_in[3];
    const float* mu   = (const float*)d_in[4];
    const float* va   = (const float*)d_in[5];
    const float* w_h  = (const float*)d_in[6];
    const float* w_w  = (const float*)d_in[7];
    float* out    = (float*)d_out;
    float* pooled = (float*)d_ws;                        // 2.62 MB
    float* y      = pooled + (size_t)N_ * C_ * L_;       // 80 KB

    void* args[] = { (void*)&x, (void*)&w_fc, (void*)&g, (void*)&be, (void*)&mu,
                     (void*)&va, (void*)&w_h, (void*)&w_w,
                     (void*)&pooled, (void*)&y, (void*)&out };
    hipError_t err = hipLaunchCooperativeKernel((const void*)fused_kernel,
                                                dim3(512), dim3(256), args, 0, stream);
    if (err != hipSuccess) {
        // fallback: proven R4 3-kernel path
        pool_kernel <<<N_ * C_,     256, 0, stream>>>(x, pooled);
        mid_kernel  <<<N_ * L_,     256, 0, stream>>>(pooled, w_fc, g, be, mu, va, y);
        apply_kernel<<<N_ * C_ / 4, 256, 0, stream>>>(x, y, w_h, w_w, out);
    }
}

// Round 6
// 219.801 us; speedup vs baseline: 1.6121x; 1.6121x over previous
//
#include <hip/hip_runtime.h>

// LightCoordAtt: x (N,C,H,W) f32 in, f32 out. N=16, C=256, H=W=80, mip=8, L=160.
//
// R6 = R4 structure (220.9 us) with pool restructured to partial-sums form;
// mid and apply byte-identical to R4 (single-variable A/B on pool).
//
// Journal: R1: cross-XCD atomicAdd fusion -> 84 MB write-back, +62 us (NEVER).
//          R3: NT stores -> -2 us (noise; kept).
//          R4: 4-plane apply blocks -> -2.4 us (kept).
//          R5: cooperative register-resident-x fusion -> +133 us (NEVER:
//              200-VGPR payload forces 2 waves/SIMD; all phases latency-bound;
//              compiler demoted payload anyway, VGPR_Count=128).
//          R6 theory: pool is the sink (~40 us implied by R1 algebra =
//              2.6 TB/s effective). Full-plane LDS staging (6400 b32 scatter
//              writes, 1.47M conflict cycles measured in R1's copy) + 2 full
//              LDS re-passes is the cost. Partial-sums pool: coalesced f32x4
//              loads, colsum in registers, only row-partials + 320 col
//              vectors through LDS, conflict-free (stride-21 pad).
#define N_   16
#define C_   256
#define H_   80
#define W_   80
#define MIP_ 8
#define L_   160

typedef float f32x4 __attribute__((ext_vector_type(4)));

// ---------------------------------------------------------------------------
// Kernel 1: per-(n,c) plane H-mean and W-mean, partial-sums form.
// 320 threads: t -> (rg = t/20, c4 = t%20). Load k: float4 v = t + 320k
// (1024 B contiguous per wave per instr). colacc (4 cols) stays in regs;
// row partial (hsum of 4) -> lds_row[row][c4]. pooled layout (n,c,l).
// ---------------------------------------------------------------------------
__global__ __launch_bounds__(320) void pool_kernel(const float* __restrict__ x,
                                                   float* __restrict__ pooled) {
    __shared__ float lds_row[H_][21];      // stride 21: gcd(21,32)=1 -> conflict-free
    __shared__ f32x4 lds_col[16][20];      // [rowgroup][colblock]
    const int b  = blockIdx.x;             // n*C_ + c
    const int t  = threadIdx.x;            // 0..319
    const int c4 = t % 20;                 // column block (4 cols)
    const int rg = t / 20;                 // row group 0..15

    const f32x4* xv = reinterpret_cast<const f32x4*>(x + (size_t)b * (H_ * W_));
    f32x4 colacc = {0.f, 0.f, 0.f, 0.f};
    #pragma unroll
    for (int k = 0; k < 5; ++k) {
        f32x4 q = xv[t + 320 * k];         // row = rg+16k, cols 4*c4..4*c4+3
        colacc += q;
        lds_row[rg + 16 * k][c4] = q.x + q.y + q.z + q.w;
    }
    lds_col[rg][c4] = colacc;
    __syncthreads();

    float* outp = pooled + (size_t)b * L_;
    if (t < H_) {                          // waves 0-1: row means -> x_h
        float s = 0.f;
        #pragma unroll
        for (int j = 0; j < 20; ++j) s += lds_row[t][j];
        outp[t] = s * (1.0f / (float)W_);
    } else if (t >= 128 && t < 128 + 20) { // wave 2: col means -> x_w (f32x4 each)
        const int j = t - 128;
        f32x4 s = lds_col[0][j];
        #pragma unroll
        for (int r = 1; r < 16; ++r) s += lds_col[r][j];
        s *= (1.0f / (float)H_);
        *reinterpret_cast<f32x4*>(outp + H_ + 4 * j) = s;   // 16B-aligned: (80+4j)*4
    }
}

// ---------------------------------------------------------------------------
// Kernel 2: y[n,l,m] = swish( BN( sum_c w_fc[m,c] * pooled[n,c,l] ) )
// (byte-identical to R4)
// ---------------------------------------------------------------------------
__global__ __launch_bounds__(256) void mid_kernel(const float* __restrict__ pooled,
                                                  const float* __restrict__ w_fc,
                                                  const float* __restrict__ g,
                                                  const float* __restrict__ be,
                                                  const float* __restrict__ mu,
                                                  const float* __restrict__ va,
                                                  float* __restrict__ y_out) {
    __shared__ float red[4 * MIP_];
    const int b    = blockIdx.x;          // n*L_ + l
    const int n    = b / L_;
    const int l    = b - n * L_;
    const int c    = threadIdx.x;
    const int lane = c & 63;
    const int wid  = c >> 6;

    const float p = pooled[((size_t)n * C_ + c) * L_ + l];

    #pragma unroll
    for (int m = 0; m < MIP_; ++m) {
        float v = w_fc[m * C_ + c] * p;
        #pragma unroll
        for (int off = 32; off > 0; off >>= 1) v += __shfl_down(v, off, 64);
        if (lane == 0) red[wid * MIP_ + m] = v;
    }
    __syncthreads();

    if (c < MIP_) {
        float y   = red[c] + red[MIP_ + c] + red[2 * MIP_ + c] + red[3 * MIP_ + c];
        float inv = g[c] * rsqrtf(va[c] + 1e-5f);
        y = y * inv + (be[c] - mu[c] * inv);
        y_out[(size_t)b * MIP_ + c] = y / (1.0f + expf(-y));   // swish
    }
}

// ---------------------------------------------------------------------------
// Kernel 3: 4 planes per block (byte-identical to R4).
// ---------------------------------------------------------------------------
__global__ __launch_bounds__(256) void apply_kernel(const float* __restrict__ x,
                                                    const float* __restrict__ y,
                                                    const float* __restrict__ w_h,
                                                    const float* __restrict__ w_w,
                                                    float* __restrict__ out) {
    __shared__ float lah[4][H_];
    __shared__ float law[4][W_];
    const int b  = blockIdx.x;            // 0..1023
    const int n  = b >> 6;                // b / 64
    const int c0 = (b & 63) << 2;         // 4 * (b % 64)
    const int t  = threadIdx.x;

    #pragma unroll
    for (int pass = 0; pass < 3; ++pass) {
        int idx = t + pass * 256;
        if (idx < 4 * L_) {
            int ch = idx / L_;
            int l  = idx - ch * L_;
            int c  = c0 + ch;
            const float4* yp = reinterpret_cast<const float4*>(y + ((size_t)n * L_ + l) * MIP_);
            const float4* wp = reinterpret_cast<const float4*>(((l < H_) ? w_h : w_w) + c * MIP_);
            float4 y0 = yp[0], y1 = yp[1];
            float4 w0 = wp[0], w1 = wp[1];
            float s = y0.x * w0.x + y0.y * w0.y + y0.z * w0.z + y0.w * w0.w
                    + y1.x * w1.x + y1.y * w1.y + y1.z * w1.z + y1.w * w1.w;
            float gate = 1.0f / (1.0f + expf(-s));
            if (l < H_) lah[ch][l] = gate; else law[ch][l - H_] = gate;
        }
    }
    __syncthreads();

    const float4* xv = reinterpret_cast<const float4*>(x + ((size_t)n * C_ + c0) * (H_ * W_));
    f32x4*        ov = reinterpret_cast<f32x4*>(out + ((size_t)n * C_ + c0) * (H_ * W_));
    #pragma unroll
    for (int it = 0; it < 25; ++it) {             // 6400 = 25 * 256 exactly
        int v     = t + it * 256;
        int plane = v / 1600;
        int vv    = v - plane * 1600;
        int row   = vv / 20;
        int col0  = (vv - row * 20) * 4;
        float4 q  = xv[v];
        const float ah = lah[plane][row];
        const float* lw = &law[plane][col0];
        f32x4 o;
        o.x = q.x * ah * lw[0];
        o.y = q.y * ah * lw[1];
        o.z = q.z * ah * lw[2];
        o.w = q.w * ah * lw[3];
        __builtin_nontemporal_store(o, &ov[v]);   // out is write-once
    }
}

extern "C" void kernel_launch(void* const* d_in, const int* in_sizes, int n_in,
                              void* d_out, int out_size, void* d_ws, size_t ws_size,
                              hipStream_t stream) {
    const float* x    = (const float*)d_in[0];
    const float* w_fc = (const float*)d_in[1];
    const float* g    = (const float*)d_in[2];
    const float* be   = (const float*)d_in[3];
    const float* mu   = (const float*)d_in[4];
    const float* va   = (const float*)d_in[5];
    const float* w_h  = (const float*)d_in[6];
    const float* w_w  = (const float*)d_in[7];
    float* out = (float*)d_out;

    float* pooled = (float*)d_ws;                        // N*C*L floats = 2.62 MB
    float* y      = pooled + (size_t)N_ * C_ * L_;       // N*L*MIP floats = 80 KB

    pool_kernel <<<N_ * C_,     320, 0, stream>>>(x, pooled);
    mid_kernel  <<<N_ * L_,     256, 0, stream>>>(pooled, w_fc, g, be, mu, va, y);
    apply_kernel<<<N_ * C_ / 4, 256, 0, stream>>>(x, y, w_h, w_w, out);
}